// Round 3
// baseline (304.972 us; speedup 1.0000x reference)
//
#include <hip/hip_runtime.h>
#include <math.h>

#define B_ 16
#define H_ 8
#define D_ 128
#define BS_ 16
#define BPS_ 128
#define T_ (BPS_ * BS_)       // 2048 tokens per sequence
#define ROW_ (H_ * D_)        // 1024 floats = 4 KiB per token row (all heads)
#define SCALE_ 0.08838834764831845f

// One WAVE per (chunk, batch): 64-thread workgroups, ZERO LDS, ZERO barriers.
// Lane l owns head h = l>>3, dims { i*32 + (l&7)*4 .. +3 }, i=0..3.
// The 8 lanes of a head group hold the head's full score vector redundantly
// after a 3-step DPP reduce, so softmax stats are purely lane-local.
// 16 independent single-wave streams per CU keep the memory system's issue
// duty cycle near 100% (vs ~3 barrier-coupled streams in the 4-wave version).
template<int NS>
__global__ __launch_bounds__(64, 4) void attn_partial(
    const float* __restrict__ q,
    const float* __restrict__ knew,
    const float* __restrict__ vnew,
    const float* __restrict__ kc,
    const float* __restrict__ vc,
    const int* __restrict__ btab,
    const int* __restrict__ clen,
    float* __restrict__ ws_m,
    float* __restrict__ ws_l,
    float* __restrict__ ws_o)
{
    constexpr int CHUNK = T_ / NS;        // tokens per wave (8 at NS=256)
    constexpr int NB = CHUNK / 4;         // 4-token load batches
    static_assert(CHUNK % 4 == 0, "CHUNK multiple of 4");

    const int c = blockIdx.x;
    const int b = blockIdx.y;
    const int lane = threadIdx.x;         // 0..63
    const int h = lane >> 3;              // head owned by this lane group
    const int e = (lane & 7) * 4;         // float offset within 32-float segment
    const int ctx = clen[b];
    const int cs = c * CHUNK;

    // Q fragment: head h, dims {i*32+e .. +3}
    float4 q4[4];
    #pragma unroll
    for (int i = 0; i < 4; ++i)
        q4[i] = *(const float4*)(q + (size_t)b * ROW_ + h * 128 + i * 32 + e);

    float sc[CHUNK];                      // scaled scores (later reused for exp)

    // ---- QK: per 4-token batch, 16 loads in one burst, then consume ----
    #pragma unroll
    for (int bt = 0; bt < NB; ++bt) {
        float4 kb[4][4];
        #pragma unroll
        for (int u = 0; u < 4; ++u) {
            const int tg = cs + bt * 4 + u;
            const int blk = btab[b * BPS_ + (tg >> 4)];      // block-uniform
            const float* rb = (tg == ctx - 1)
                ? (knew + (size_t)b * ROW_)
                : (kc + ((size_t)blk * BS_ + (tg & 15)) * ROW_);
            #pragma unroll
            for (int i = 0; i < 4; ++i)
                kb[u][i] = *(const float4*)(rb + h * 128 + i * 32 + e);
        }
        #pragma unroll
        for (int u = 0; u < 4; ++u) {
            const int tg = cs + bt * 4 + u;
            float s = 0.f;
            #pragma unroll
            for (int i = 0; i < 4; ++i)
                s += q4[i].x * kb[u][i].x + q4[i].y * kb[u][i].y
                   + q4[i].z * kb[u][i].z + q4[i].w * kb[u][i].w;
            s += __shfl_xor(s, 1);        // DPP quad_perm
            s += __shfl_xor(s, 2);        // DPP quad_perm
            s += __shfl_xor(s, 4);        // DPP row_half_mirror
            sc[bt * 4 + u] = (tg < ctx) ? s * SCALE_ : -INFINITY;
        }
    }

    // ---- softmax stats: fully lane-local (no shuffles, no LDS) ----
    float m = -INFINITY;
    #pragma unroll
    for (int t = 0; t < CHUNK; ++t) m = fmaxf(m, sc[t]);
    m = fmaxf(m, -1e30f);                 // guard fully-masked chunk
    float l = 0.f;
    #pragma unroll
    for (int t = 0; t < CHUNK; ++t) {
        sc[t] = __expf(sc[t] - m);        // reuse sc[] as p-weights
        l += sc[t];
    }

    // ---- PV: same burst pattern; zero cross-lane ops ----
    float4 acc[4];
    #pragma unroll
    for (int i = 0; i < 4; ++i) acc[i] = make_float4(0.f, 0.f, 0.f, 0.f);

    #pragma unroll
    for (int bt = 0; bt < NB; ++bt) {
        float4 vb[4][4];
        #pragma unroll
        for (int u = 0; u < 4; ++u) {
            const int tg = cs + bt * 4 + u;
            const int blk = btab[b * BPS_ + (tg >> 4)];
            const float* rb = (tg == ctx - 1)
                ? (vnew + (size_t)b * ROW_)
                : (vc + ((size_t)blk * BS_ + (tg & 15)) * ROW_);
            #pragma unroll
            for (int i = 0; i < 4; ++i)
                vb[u][i] = *(const float4*)(rb + h * 128 + i * 32 + e);
        }
        #pragma unroll
        for (int u = 0; u < 4; ++u) {
            const float pw = sc[bt * 4 + u];
            #pragma unroll
            for (int i = 0; i < 4; ++i) {
                acc[i].x += pw * vb[u][i].x;
                acc[i].y += pw * vb[u][i].y;
                acc[i].z += pw * vb[u][i].z;
                acc[i].w += pw * vb[u][i].w;
            }
        }
    }

    // ---- write chunk partials straight from registers ----
    #pragma unroll
    for (int i = 0; i < 4; ++i)
        *(float4*)(ws_o + ((size_t)(b * H_ + h) * NS + c) * D_ + i * 32 + e) = acc[i];
    if ((lane & 7) == 0) {
        ws_m[(b * H_ + h) * NS + c] = m;
        ws_l[(b * H_ + h) * NS + c] = l;
    }
}

// Kernel 2: combine NS chunk partials per (b,h) with online-softmax rescale.
template<int NS>
__global__ __launch_bounds__(128) void attn_reduce(
    const float* __restrict__ ws_m,
    const float* __restrict__ ws_l,
    const float* __restrict__ ws_o,
    float* __restrict__ out)
{
    const int bh = blockIdx.x;    // 0..127
    const int tid = threadIdx.x;  // 0..127 = d

    __shared__ float s_co[NS];
    __shared__ float s_lg;

    if (tid < 64) {
        float m = -INFINITY;
        for (int cc = tid; cc < NS; cc += 64) m = fmaxf(m, ws_m[bh * NS + cc]);
        m = fmaxf(m, __shfl_xor(m, 32));
        m = fmaxf(m, __shfl_xor(m, 16));
        m = fmaxf(m, __shfl_xor(m, 8));
        m = fmaxf(m, __shfl_xor(m, 4));
        m = fmaxf(m, __shfl_xor(m, 2));
        m = fmaxf(m, __shfl_xor(m, 1));   // m = global max, all lanes
        float lw = 0.f;
        for (int cc = tid; cc < NS; cc += 64) {
            const float co = __expf(ws_m[bh * NS + cc] - m);
            s_co[cc] = co;
            lw += ws_l[bh * NS + cc] * co;
        }
        lw += __shfl_xor(lw, 32);
        lw += __shfl_xor(lw, 16);
        lw += __shfl_xor(lw, 8);
        lw += __shfl_xor(lw, 4);
        lw += __shfl_xor(lw, 2);
        lw += __shfl_xor(lw, 1);
        if (tid == 0) s_lg = lw;
    }
    __syncthreads();

    float acc = 0.f;
    #pragma unroll 8
    for (int cc = 0; cc < NS; ++cc)
        acc += s_co[cc] * ws_o[((size_t)bh * NS + cc) * D_ + tid];
    out[(size_t)bh * D_ + tid] = acc / s_lg;
}

template<int NS>
static void launch_all(const float* q, const float* knew, const float* vnew,
                       const float* kc, const float* vc,
                       const int* btab, const int* clen,
                       float* ws, float* out, hipStream_t stream)
{
    float* ws_m = ws;
    float* ws_l = ws + B_ * H_ * NS;
    float* ws_o = ws + 2 * B_ * H_ * NS;
    attn_partial<NS><<<dim3(NS, B_), 64, 0, stream>>>(q, knew, vnew, kc, vc,
                                                      btab, clen, ws_m, ws_l, ws_o);
    attn_reduce<NS><<<dim3(B_ * H_), 128, 0, stream>>>(ws_m, ws_l, ws_o, out);
}

extern "C" void kernel_launch(void* const* d_in, const int* in_sizes, int n_in,
                              void* d_out, int out_size, void* d_ws, size_t ws_size,
                              hipStream_t stream) {
    const float* q    = (const float*)d_in[0];
    const float* knew = (const float*)d_in[1];
    const float* vnew = (const float*)d_in[2];
    const float* kc   = (const float*)d_in[3];
    const float* vc   = (const float*)d_in[4];
    // d_in[5] = slot_mapping: unused — slot == position of token ctx-1 in the
    // batch's own block-table row (rows disjoint), handled by in-flight substitution.
    const int* btab = (const int*)d_in[6];
    const int* clen = (const int*)d_in[7];
    float* out = (float*)d_out;
    float* ws  = (float*)d_ws;

    // scratch need for split NS: B*H*NS*(2 + D) floats
    const size_t need256 = (size_t)B_ * H_ * 256 * (2 + D_) * sizeof(float); // ~17 MiB
    const size_t need128 = (size_t)B_ * H_ * 128 * (2 + D_) * sizeof(float); // ~8.5 MiB
    const size_t need64  = (size_t)B_ * H_ * 64  * (2 + D_) * sizeof(float); // ~4.3 MiB
    if (ws_size >= need256)     launch_all<256>(q, knew, vnew, kc, vc, btab, clen, ws, out, stream);
    else if (ws_size >= need128) launch_all<128>(q, knew, vnew, kc, vc, btab, clen, ws, out, stream);
    else                         launch_all<64>(q, knew, vnew, kc, vc, btab, clen, ws, out, stream);
}

// Round 5
// 286.632 us; speedup vs baseline: 1.0640x; 1.0640x over previous
//
#include <hip/hip_runtime.h>
#include <math.h>

#define B_ 16
#define H_ 8
#define D_ 128
#define BS_ 16
#define BPS_ 128
#define T_ (BPS_ * BS_)       // 2048 tokens per sequence
#define ROW_ (H_ * D_)        // 1024 floats = 4 KiB per token row (all heads)
#define SCALE_ 0.08838834764831845f

typedef float f32x4 __attribute__((ext_vector_type(4)));

// One WAVE per (chunk, batch): 64-thread WGs, zero LDS, zero barriers.
// Lane l owns head h = l>>3, dims { i*32 + (l&7)*4 .. +3 }.
// KV loads are NON-TEMPORAL: the 268 MB working set cyclically overflows the
// 256 MB Infinity Cache, so allocating fills are pure churn (line evicted
// before reuse) and fragment the HBM miss stream. nt streams straight through.
template<int NS>
__global__ __launch_bounds__(64, 4) void attn_partial(
    const float* __restrict__ q,
    const float* __restrict__ knew,
    const float* __restrict__ vnew,
    const float* __restrict__ kc,
    const float* __restrict__ vc,
    const int* __restrict__ btab,
    const int* __restrict__ clen,
    float2* __restrict__ ws_ml,          // [NS][B*H] packed (m,l)
    float* __restrict__ ws_o)
{
    constexpr int CHUNK = T_ / NS;        // tokens per wave (8 at NS=256)
    constexpr int NB = CHUNK / 4;         // 4-token load batches
    static_assert(CHUNK % 4 == 0, "CHUNK multiple of 4");

    const int c = blockIdx.x;
    const int b = blockIdx.y;
    const int lane = threadIdx.x;         // 0..63
    const int h = lane >> 3;              // head owned by this lane group
    const int e = (lane & 7) * 4;         // float offset within 32-float segment
    const int ctx = clen[b];
    const int cs = c * CHUNK;

    // Q fragment: head h, dims {i*32+e .. +3}
    f32x4 q4[4];
    #pragma unroll
    for (int i = 0; i < 4; ++i)
        q4[i] = *(const f32x4*)(q + (size_t)b * ROW_ + h * 128 + i * 32 + e);

    float sc[CHUNK];                      // scaled scores (later reused for exp)

    // ---- QK: per 4-token batch, 16 NT loads in one burst, then consume ----
    #pragma unroll
    for (int bt = 0; bt < NB; ++bt) {
        f32x4 kb[4][4];
        #pragma unroll
        for (int u = 0; u < 4; ++u) {
            const int tg = cs + bt * 4 + u;
            const int blk = btab[b * BPS_ + (tg >> 4)];      // block-uniform
            const float* rb = (tg == ctx - 1)
                ? (knew + (size_t)b * ROW_)
                : (kc + ((size_t)blk * BS_ + (tg & 15)) * ROW_);
            #pragma unroll
            for (int i = 0; i < 4; ++i)
                kb[u][i] = __builtin_nontemporal_load(
                    (const f32x4*)(rb + h * 128 + i * 32 + e));
        }
        #pragma unroll
        for (int u = 0; u < 4; ++u) {
            const int tg = cs + bt * 4 + u;
            float s = 0.f;
            #pragma unroll
            for (int i = 0; i < 4; ++i)
                s += q4[i].x * kb[u][i].x + q4[i].y * kb[u][i].y
                   + q4[i].z * kb[u][i].z + q4[i].w * kb[u][i].w;
            s += __shfl_xor(s, 1);        // DPP quad_perm
            s += __shfl_xor(s, 2);        // DPP quad_perm
            s += __shfl_xor(s, 4);        // DPP row_half_mirror
            sc[bt * 4 + u] = (tg < ctx) ? s * SCALE_ : -INFINITY;
        }
    }

    // ---- softmax stats: fully lane-local (no shuffles, no LDS) ----
    float m = -INFINITY;
    #pragma unroll
    for (int t = 0; t < CHUNK; ++t) m = fmaxf(m, sc[t]);
    m = fmaxf(m, -1e30f);                 // guard fully-masked chunk
    float l = 0.f;
    #pragma unroll
    for (int t = 0; t < CHUNK; ++t) {
        sc[t] = __expf(sc[t] - m);        // reuse sc[] as p-weights
        l += sc[t];
    }

    // ---- PV: same NT burst pattern; zero cross-lane ops ----
    f32x4 acc[4];
    #pragma unroll
    for (int i = 0; i < 4; ++i) acc[i] = (f32x4)(0.f);

    #pragma unroll
    for (int bt = 0; bt < NB; ++bt) {
        f32x4 vb[4][4];
        #pragma unroll
        for (int u = 0; u < 4; ++u) {
            const int tg = cs + bt * 4 + u;
            const int blk = btab[b * BPS_ + (tg >> 4)];
            const float* rb = (tg == ctx - 1)
                ? (vnew + (size_t)b * ROW_)
                : (vc + ((size_t)blk * BS_ + (tg & 15)) * ROW_);
            #pragma unroll
            for (int i = 0; i < 4; ++i)
                vb[u][i] = __builtin_nontemporal_load(
                    (const f32x4*)(rb + h * 128 + i * 32 + e));
        }
        #pragma unroll
        for (int u = 0; u < 4; ++u) {
            const float pw = sc[bt * 4 + u];
            #pragma unroll
            for (int i = 0; i < 4; ++i)
                acc[i] += pw * vb[u][i];
        }
    }

    // ---- write chunk partials straight from registers ----
    #pragma unroll
    for (int i = 0; i < 4; ++i)
        *(f32x4*)(ws_o + ((size_t)(b * H_ + h) * NS + c) * D_ + i * 32 + e) = acc[i];
    // packed (m,l): one 64-B contiguous region per wave (8 heads x 8 B)
    if ((lane & 7) == 0)
        ws_ml[(size_t)c * (B_ * H_) + b * H_ + h] = make_float2(m, l);
}

// Kernel 2: combine NS chunk partials per (b,h) with online-softmax rescale.
template<int NS>
__global__ __launch_bounds__(128) void attn_reduce(
    const float2* __restrict__ ws_ml,
    const float* __restrict__ ws_o,
    float* __restrict__ out)
{
    const int bh = blockIdx.x;    // 0..127
    const int tid = threadIdx.x;  // 0..127 = d

    __shared__ float s_co[NS];
    __shared__ float s_lg;

    if (tid < 64) {
        float2 ml[NS / 64];
        float m = -INFINITY;
        #pragma unroll
        for (int r = 0; r < NS / 64; ++r) {
            ml[r] = ws_ml[(size_t)(r * 64 + tid) * (B_ * H_) + bh];
            m = fmaxf(m, ml[r].x);
        }
        m = fmaxf(m, __shfl_xor(m, 32));
        m = fmaxf(m, __shfl_xor(m, 16));
        m = fmaxf(m, __shfl_xor(m, 8));
        m = fmaxf(m, __shfl_xor(m, 4));
        m = fmaxf(m, __shfl_xor(m, 2));
        m = fmaxf(m, __shfl_xor(m, 1));   // m = global max, all lanes
        float lw = 0.f;
        #pragma unroll
        for (int r = 0; r < NS / 64; ++r) {
            const float co = __expf(ml[r].x - m);
            s_co[r * 64 + tid] = co;
            lw += ml[r].y * co;
        }
        lw += __shfl_xor(lw, 32);
        lw += __shfl_xor(lw, 16);
        lw += __shfl_xor(lw, 8);
        lw += __shfl_xor(lw, 4);
        lw += __shfl_xor(lw, 2);
        lw += __shfl_xor(lw, 1);
        if (tid == 0) s_lg = lw;
    }
    __syncthreads();

    float acc = 0.f;
    #pragma unroll 8
    for (int cc = 0; cc < NS; ++cc)
        acc += s_co[cc] * ws_o[((size_t)bh * NS + cc) * D_ + tid];
    out[(size_t)bh * D_ + tid] = acc / s_lg;
}

template<int NS>
static void launch_all(const float* q, const float* knew, const float* vnew,
                       const float* kc, const float* vc,
                       const int* btab, const int* clen,
                       float* ws, float* out, hipStream_t stream)
{
    float2* ws_ml = (float2*)ws;
    float* ws_o = ws + 2 * B_ * H_ * NS;
    attn_partial<NS><<<dim3(NS, B_), 64, 0, stream>>>(q, knew, vnew, kc, vc,
                                                      btab, clen, ws_ml, ws_o);
    attn_reduce<NS><<<dim3(B_ * H_), 128, 0, stream>>>(ws_ml, ws_o, out);
}

extern "C" void kernel_launch(void* const* d_in, const int* in_sizes, int n_in,
                              void* d_out, int out_size, void* d_ws, size_t ws_size,
                              hipStream_t stream) {
    const float* q    = (const float*)d_in[0];
    const float* knew = (const float*)d_in[1];
    const float* vnew = (const float*)d_in[2];
    const float* kc   = (const float*)d_in[3];
    const float* vc   = (const float*)d_in[4];
    // d_in[5] = slot_mapping: unused — slot == position of token ctx-1 in the
    // batch's own block-table row (rows disjoint), handled by in-flight substitution.
    const int* btab = (const int*)d_in[6];
    const int* clen = (const int*)d_in[7];
    float* out = (float*)d_out;
    float* ws  = (float*)d_ws;

    // scratch need for split NS: B*H*NS*(2 + D) floats
    const size_t need256 = (size_t)B_ * H_ * 256 * (2 + D_) * sizeof(float); // ~17 MiB
    const size_t need128 = (size_t)B_ * H_ * 128 * (2 + D_) * sizeof(float); // ~8.5 MiB
    if (ws_size >= need256)      launch_all<256>(q, knew, vnew, kc, vc, btab, clen, ws, out, stream);
    else if (ws_size >= need128) launch_all<128>(q, knew, vnew, kc, vc, btab, clen, ws, out, stream);
    else                         launch_all<64>(q, knew, vnew, kc, vc, btab, clen, ws, out, stream);
}

// Round 6
// 273.683 us; speedup vs baseline: 1.1143x; 1.0473x over previous
//
#include <hip/hip_runtime.h>
#include <math.h>

#define B_ 16
#define H_ 8
#define D_ 128
#define BS_ 16
#define BPS_ 128
#define T_ (BPS_ * BS_)       // 2048 tokens per sequence
#define ROW_ (H_ * D_)        // 1024 floats = 4 KiB per token row (all heads)
#define SCALE_ 0.08838834764831845f

typedef float f32x4 __attribute__((ext_vector_type(4)));

// One WAVE per (chunk, batch): 64-thread WGs, zero LDS, zero barriers.
// Lane l owns head h = l>>3, dims { i*32 + (l&7)*4 .. +3 }.
// KV loads NON-TEMPORAL (268 MB sweep vs 256 MB MALL: allocating fills are
// pure churn — confirmed R5: partial 101 -> <77 us).
// NS=256 path is software-pipelined: issue K0+V0+K1 bursts (48 loads in
// flight) before any consume; single vmcnt drain per wave instead of four.
template<int NS>
__global__ __launch_bounds__(64, 2) void attn_partial(
    const float* __restrict__ q,
    const float* __restrict__ knew,
    const float* __restrict__ vnew,
    const float* __restrict__ kc,
    const float* __restrict__ vc,
    const int* __restrict__ btab,
    const int* __restrict__ clen,
    float2* __restrict__ ws_ml,          // [NS][B*H] packed (m,l)
    float* __restrict__ ws_o)
{
    constexpr int CHUNK = T_ / NS;        // tokens per wave (8 at NS=256)
    constexpr int NB = CHUNK / 4;         // 4-token load batches
    static_assert(CHUNK % 4 == 0, "CHUNK multiple of 4");

    const int c = blockIdx.x;
    const int b = blockIdx.y;
    const int lane = threadIdx.x;         // 0..63
    const int h = lane >> 3;              // head owned by this lane group
    const int e = (lane & 7) * 4;         // float offset within 32-float segment
    const int ctx = clen[b];
    const int cs = c * CHUNK;

    // row-pointer helpers (in-flight substitution of the new token)
    auto krow = [&](int u) -> const float* {
        const int tg = cs + u;
        const int blk = btab[b * BPS_ + (tg >> 4)];
        return (tg == ctx - 1) ? (knew + (size_t)b * ROW_)
                               : (kc + ((size_t)blk * BS_ + (tg & 15)) * ROW_);
    };
    auto vrow = [&](int u) -> const float* {
        const int tg = cs + u;
        const int blk = btab[b * BPS_ + (tg >> 4)];
        return (tg == ctx - 1) ? (vnew + (size_t)b * ROW_)
                               : (vc + ((size_t)blk * BS_ + (tg & 15)) * ROW_);
    };
    auto ld4 = [&](f32x4 (&dst)[4], const float* rb) {
        #pragma unroll
        for (int i = 0; i < 4; ++i)
            dst[i] = __builtin_nontemporal_load(
                (const f32x4*)(rb + h * 128 + i * 32 + e));
    };

    // Q fragment: head h, dims {i*32+e .. +3}
    f32x4 q4[4];
    #pragma unroll
    for (int i = 0; i < 4; ++i)
        q4[i] = *(const f32x4*)(q + (size_t)b * ROW_ + h * 128 + i * 32 + e);

    auto dot = [&](const f32x4 (&kb)[4]) -> float {
        float s = 0.f;
        #pragma unroll
        for (int i = 0; i < 4; ++i)
            s += q4[i].x * kb[i].x + q4[i].y * kb[i].y
               + q4[i].z * kb[i].z + q4[i].w * kb[i].w;
        s += __shfl_xor(s, 1);            // DPP quad_perm
        s += __shfl_xor(s, 2);            // DPP quad_perm
        s += __shfl_xor(s, 4);            // DPP row_half_mirror
        return s;
    };

    float sc[CHUNK];                      // scaled scores (later reused for exp)
    f32x4 acc[4];
    #pragma unroll
    for (int i = 0; i < 4; ++i) acc[i] = (f32x4)(0.f);

    if constexpr (NB == 2) {
        // ---- pipelined path (CHUNK=8): 48 loads issued before first consume --
        f32x4 k0[4][4], k1[4][4], v0[4][4], v1[4][4];
        #pragma unroll
        for (int u = 0; u < 4; ++u) ld4(k0[u], krow(u));
        #pragma unroll
        for (int u = 0; u < 4; ++u) ld4(v0[u], vrow(u));
        #pragma unroll
        for (int u = 0; u < 4; ++u) ld4(k1[u], krow(4 + u));

        #pragma unroll
        for (int u = 0; u < 4; ++u) {     // consume K0 (waits vmcnt(32))
            const float s = dot(k0[u]);
            sc[u] = (cs + u < ctx) ? s * SCALE_ : -INFINITY;
        }
        #pragma unroll
        for (int u = 0; u < 4; ++u) {     // consume K1 (waits vmcnt(16))
            const float s = dot(k1[u]);
            sc[4 + u] = (cs + 4 + u < ctx) ? s * SCALE_ : -INFINITY;
        }

        // softmax stats: fully lane-local
        float m = -INFINITY;
        #pragma unroll
        for (int t = 0; t < 8; ++t) m = fmaxf(m, sc[t]);
        m = fmaxf(m, -1e30f);
        float l = 0.f;
        #pragma unroll
        for (int t = 0; t < 8; ++t) { sc[t] = __expf(sc[t] - m); l += sc[t]; }

        #pragma unroll
        for (int u = 0; u < 4; ++u) {     // consume V0 (waits vmcnt(0))
            const float pw = sc[u];
            #pragma unroll
            for (int i = 0; i < 4; ++i) acc[i] += pw * v0[u][i];
        }
        #pragma unroll
        for (int u = 0; u < 4; ++u) ld4(v1[u], vrow(4 + u));
        #pragma unroll
        for (int u = 0; u < 4; ++u) {     // consume V1
            const float pw = sc[4 + u];
            #pragma unroll
            for (int i = 0; i < 4; ++i) acc[i] += pw * v1[u][i];
        }

        #pragma unroll
        for (int i = 0; i < 4; ++i)
            __builtin_nontemporal_store(acc[i],
                (f32x4*)(ws_o + ((size_t)(b * H_ + h) * NS + c) * D_ + i * 32 + e));
        if ((lane & 7) == 0)
            ws_ml[(size_t)c * (B_ * H_) + b * H_ + h] = make_float2(m, l);
        return;
    }

    // ---- generic fallback (smaller NS tiers): serial burst structure ----
    #pragma unroll
    for (int bt = 0; bt < NB; ++bt) {
        f32x4 kb[4][4];
        #pragma unroll
        for (int u = 0; u < 4; ++u) ld4(kb[u], krow(bt * 4 + u));
        #pragma unroll
        for (int u = 0; u < 4; ++u) {
            const float s = dot(kb[u]);
            sc[bt * 4 + u] = (cs + bt * 4 + u < ctx) ? s * SCALE_ : -INFINITY;
        }
    }
    float m = -INFINITY;
    #pragma unroll
    for (int t = 0; t < CHUNK; ++t) m = fmaxf(m, sc[t]);
    m = fmaxf(m, -1e30f);
    float l = 0.f;
    #pragma unroll
    for (int t = 0; t < CHUNK; ++t) { sc[t] = __expf(sc[t] - m); l += sc[t]; }

    #pragma unroll
    for (int bt = 0; bt < NB; ++bt) {
        f32x4 vb[4][4];
        #pragma unroll
        for (int u = 0; u < 4; ++u) ld4(vb[u], vrow(bt * 4 + u));
        #pragma unroll
        for (int u = 0; u < 4; ++u) {
            const float pw = sc[bt * 4 + u];
            #pragma unroll
            for (int i = 0; i < 4; ++i) acc[i] += pw * vb[u][i];
        }
    }
    #pragma unroll
    for (int i = 0; i < 4; ++i)
        __builtin_nontemporal_store(acc[i],
            (f32x4*)(ws_o + ((size_t)(b * H_ + h) * NS + c) * D_ + i * 32 + e));
    if ((lane & 7) == 0)
        ws_ml[(size_t)c * (B_ * H_) + b * H_ + h] = make_float2(m, l);
}

// Kernel 2: combine NS chunk partials per (b,h). 256 threads = 8 cc-strips x
// 32 lanes; f32x4 NT loads (512B/instr coalesced); LDS strip-combine.
template<int NS>
__global__ __launch_bounds__(256) void attn_reduce(
    const float2* __restrict__ ws_ml,
    const float* __restrict__ ws_o,
    float* __restrict__ out)
{
    const int bh = blockIdx.x;    // 0..127
    const int tid = threadIdx.x;  // 0..255

    __shared__ float s_co[NS];
    __shared__ float s_lg;
    __shared__ f32x4 s_t[8][32];

    if (tid < 64) {
        float2 ml[NS / 64];
        float m = -INFINITY;
        #pragma unroll
        for (int r = 0; r < NS / 64; ++r) {
            ml[r] = ws_ml[(size_t)(r * 64 + tid) * (B_ * H_) + bh];
            m = fmaxf(m, ml[r].x);
        }
        m = fmaxf(m, __shfl_xor(m, 32));
        m = fmaxf(m, __shfl_xor(m, 16));
        m = fmaxf(m, __shfl_xor(m, 8));
        m = fmaxf(m, __shfl_xor(m, 4));
        m = fmaxf(m, __shfl_xor(m, 2));
        m = fmaxf(m, __shfl_xor(m, 1));   // global max, all lanes
        float lw = 0.f;
        #pragma unroll
        for (int r = 0; r < NS / 64; ++r) {
            const float co = __expf(ml[r].x - m);
            s_co[r * 64 + tid] = co;
            lw += ml[r].y * co;
        }
        lw += __shfl_xor(lw, 32);
        lw += __shfl_xor(lw, 16);
        lw += __shfl_xor(lw, 8);
        lw += __shfl_xor(lw, 4);
        lw += __shfl_xor(lw, 2);
        lw += __shfl_xor(lw, 1);
        if (tid == 0) s_lg = lw;
    }
    __syncthreads();

    const int ss = tid >> 5;              // cc-strip 0..7
    const int ln = tid & 31;              // d-quad owner
    f32x4 a = (f32x4)(0.f);
    #pragma unroll 4
    for (int cc = ss; cc < NS; cc += 8)
        a += s_co[cc] * __builtin_nontemporal_load(
            (const f32x4*)(ws_o + ((size_t)bh * NS + cc) * D_ + ln * 4));
    s_t[ss][ln] = a;
    __syncthreads();

    if (tid < 32) {
        f32x4 r = (f32x4)(0.f);
        #pragma unroll
        for (int s = 0; s < 8; ++s) r += s_t[s][tid];
        r *= (1.0f / s_lg);
        *(f32x4*)(out + (size_t)bh * D_ + tid * 4) = r;
    }
}

template<int NS>
static void launch_all(const float* q, const float* knew, const float* vnew,
                       const float* kc, const float* vc,
                       const int* btab, const int* clen,
                       float* ws, float* out, hipStream_t stream)
{
    float2* ws_ml = (float2*)ws;
    float* ws_o = ws + 2 * B_ * H_ * NS;
    attn_partial<NS><<<dim3(NS, B_), 64, 0, stream>>>(q, knew, vnew, kc, vc,
                                                      btab, clen, ws_ml, ws_o);
    attn_reduce<NS><<<dim3(B_ * H_), 256, 0, stream>>>(ws_ml, ws_o, out);
}

extern "C" void kernel_launch(void* const* d_in, const int* in_sizes, int n_in,
                              void* d_out, int out_size, void* d_ws, size_t ws_size,
                              hipStream_t stream) {
    const float* q    = (const float*)d_in[0];
    const float* knew = (const float*)d_in[1];
    const float* vnew = (const float*)d_in[2];
    const float* kc   = (const float*)d_in[3];
    const float* vc   = (const float*)d_in[4];
    // d_in[5] = slot_mapping: unused — slot == position of token ctx-1 in the
    // batch's own block-table row (rows disjoint), handled by in-flight substitution.
    const int* btab = (const int*)d_in[6];
    const int* clen = (const int*)d_in[7];
    float* out = (float*)d_out;
    float* ws  = (float*)d_ws;

    // scratch need for split NS: B*H*NS*(2 + D) floats
    const size_t need256 = (size_t)B_ * H_ * 256 * (2 + D_) * sizeof(float); // ~17 MiB
    const size_t need128 = (size_t)B_ * H_ * 128 * (2 + D_) * sizeof(float); // ~8.5 MiB
    if (ws_size >= need256)      launch_all<256>(q, knew, vnew, kc, vc, btab, clen, ws, out, stream);
    else if (ws_size >= need128) launch_all<128>(q, knew, vnew, kc, vc, btab, clen, ws, out, stream);
    else                         launch_all<64>(q, knew, vnew, kc, vc, btab, clen, ws, out, stream);
}